// Round 13
// baseline (884.457 us; speedup 1.0000x reference)
//
#include <hip/hip_runtime.h>

using half8 = __attribute__((ext_vector_type(8))) _Float16;
using f32x4 = __attribute__((ext_vector_type(4))) float;

__device__ __forceinline__ float sigmf(float x) {
    return __builtin_amdgcn_rcpf(1.0f + __expf(-x));
}
__device__ __forceinline__ float tanhx(float x) {
    return 1.0f - 2.0f * __builtin_amdgcn_rcpf(1.0f + __expf(x + x));
}

// ---------------------------------------------------------------------------
// Prep (one-time):
//  wihI0 : GEMM-interleaved [512][76] fp16 (row n = gate row (n&3)*128+(n>>2))
//  wihP1 : plain [512][128] fp16 (pair B-role, in-register)
//  wihI2 : GEMM-interleaved [256][128] fp16
//  wihP{3,4,5}: plain (quad in-register roles)
//  whhP  : all layers plain [4H][H] fp16
//  biasI : interleaved: L0@0 (512), L2@512 (256)
//  biasP : plain: L3@0 (256), L4@256 (128), L5@384 (128), L1@512 (512)
//  lwI   : lin_w as [75][4][16][32] fp16
// (x is consumed as f32 directly by gemm_xg0.)
// ---------------------------------------------------------------------------
struct PrepPtrs {
    const float* wih[6];
    const float* whh[6];
    const float* bi[6];
    const float* bh[6];
    const float* lw;
    _Float16* wihI0;
    _Float16* wihP1;
    _Float16* wihI2;
    _Float16* wihP3;
    _Float16* wihP4;
    _Float16* wihP5;
    _Float16* whhP[6];
    float* biasI;
    float* biasP;
    _Float16* lwI;
};

__global__ __launch_bounds__(256) void prep_kernel(PrepPtrs p) {
    int i = blockIdx.x * 256 + threadIdx.x;
    if (i < 38912) {  // wihI0 [512][76], K=75, interleaved
        int n = i / 76, k = i - n * 76;
        int col = n >> 2, G = n & 3;
        float v = (k < 75) ? p.wih[0][(size_t)(G * 128 + col) * 75 + k] : 0.0f;
        p.wihI0[i] = (_Float16)v;
        return;
    }
    i -= 38912;
    if (i < 65536) { p.wihP1[i] = (_Float16)p.wih[1][i]; return; }  // plain [512][128]
    i -= 65536;
    if (i < 32768) {  // wihI2 [256][128] interleaved
        int n = i >> 7, k = i & 127;
        int col = n >> 2, G = n & 3;
        p.wihI2[i] = (_Float16)p.wih[2][(size_t)(G * 64 + col) * 128 + k];
        return;
    }
    i -= 32768;
    if (i < 16384) { p.wihP3[i] = (_Float16)p.wih[3][i]; return; }
    i -= 16384;
    if (i < 8192) { p.wihP4[i] = (_Float16)p.wih[4][i]; return; }
    i -= 8192;
    if (i < 4096) { p.wihP5[i] = (_Float16)p.wih[5][i]; return; }
    i -= 4096;
    constexpr int WHHC[6] = {65536, 65536, 16384, 16384, 4096, 4096};
    #pragma unroll
    for (int l = 0; l < 6; ++l) {
        if (i < WHHC[l]) { p.whhP[l][i] = (_Float16)p.whh[l][i]; return; }
        i -= WHHC[l];
    }
    if (i < 153600) {  // lwI [75][4][16][32]
        int t = i >> 11;
        int rem = i & 2047;
        int tile = rem >> 9, op = (rem >> 5) & 15, hc = rem & 31;
        int o = tile * 16 + op;
        float v = (o < 60) ? p.lw[(size_t)o * 2400 + t * 32 + hc] : 0.0f;
        p.lwI[i] = (_Float16)v;
        return;
    }
    i -= 153600;
    if (i < 512) {  // biasI L0 (H=128) interleaved
        int col = i >> 2, G = i & 3;
        int src = G * 128 + col;
        p.biasI[i] = p.bi[0][src] + p.bh[0][src];
        return;
    }
    i -= 512;
    if (i < 256) {  // biasI L2 (H=64) interleaved @512
        int col = i >> 2, G = i & 3;
        int src = G * 64 + col;
        p.biasI[512 + i] = p.bi[2][src] + p.bh[2][src];
        return;
    }
    i -= 256;
    if (i < 256) { p.biasP[i] = p.bi[3][i] + p.bh[3][i]; return; }
    i -= 256;
    if (i < 128) { p.biasP[256 + i] = p.bi[4][i] + p.bh[4][i]; return; }
    i -= 128;
    if (i < 128) { p.biasP[384 + i] = p.bi[5][i] + p.bh[5][i]; return; }
    i -= 128;
    if (i < 512) { p.biasP[512 + i] = p.bi[1][i] + p.bh[1][i]; return; }
}

// ---------------------------------------------------------------------------
// Layer-0 xg GEMM reading f32 x directly (converts during LDS staging).
// Output layout [75][28][512][4] f32 (round-7 proven fragment layout).
// ---------------------------------------------------------------------------
__global__ __launch_bounds__(256) void gemm_xg0(
    const float* __restrict__ X,        // [100][75][75] f32
    const _Float16* __restrict__ W,     // wihI0 [512][76]
    const float* __restrict__ bias, float* __restrict__ C) {
    constexpr int Ks = 3, LDK = 104, HP = 48, Kv = 76, N = 512;
    __shared__ __align__(16) _Float16 Al[64][LDK];
    __shared__ __align__(16) _Float16 Wl[64][LDK];

    const int tid = threadIdx.x;
    const int tt = blockIdx.x >> 1;
    const int boff = (blockIdx.x & 1) * 48;
    const int n0 = blockIdx.y * 64;

    for (int idx = tid; idx < 64 * HP; idx += 256) {
        int row = idx / HP;
        int k = (idx - row * HP) * 2;
        unsigned int va = 0, vw = 0;
        int b = boff + row;
        if (b < 100 && k < 75) {
            float f0 = X[((size_t)b * 75 + tt) * 75 + k];
            float f1 = (k + 1 < 75) ? X[((size_t)b * 75 + tt) * 75 + k + 1] : 0.0f;
            _Float16 h2[2] = {(_Float16)f0, (_Float16)f1};
            va = *(unsigned int*)h2;
        }
        if (k < Kv) vw = *(const unsigned int*)(W + (size_t)(n0 + row) * Kv + k);
        *(unsigned int*)&Al[row][k] = va;
        *(unsigned int*)&Wl[row][k] = vw;
    }
    __syncthreads();

    const int w = tid >> 6, l = tid & 63, hi = l >> 4;
    half8 a[Ks];
    #pragma unroll
    for (int kk = 0; kk < Ks; ++kk)
        a[kk] = *(const half8*)&Al[w * 16 + (l & 15)][kk * 32 + hi * 8];

    f32x4 acc[4];
    #pragma unroll
    for (int jt = 0; jt < 4; ++jt) {
        acc[jt] = f32x4{0.f, 0.f, 0.f, 0.f};
        #pragma unroll
        for (int kk = 0; kk < Ks; ++kk) {
            half8 b = *(const half8*)&Wl[jt * 16 + (l & 15)][kk * 32 + hi * 8];
            acc[jt] = __builtin_amdgcn_mfma_f32_16x16x32_f16(a[kk], b, acc[jt], 0, 0, 0);
        }
    }

    const int bx = (boff >> 2) + w * 4 + hi;
    #pragma unroll
    for (int jt = 0; jt < 4; ++jt) {
        int n = n0 + jt * 16 + (l & 15);
        float bs = bias[n];
        f32x4 v = acc[jt];
        v[0] += bs; v[1] += bs; v[2] += bs; v[3] += bs;
        *(f32x4*)(C + ((size_t)(tt * 28 + bx) * N + n) * 4) = v;
    }
}

// ---------------------------------------------------------------------------
// xg GEMM from fp16 A (round-7 proven): layout [75][28][4H][4] f32.
// ---------------------------------------------------------------------------
template <int Ks>
__global__ __launch_bounds__(256) void gemm_xg(
    const _Float16* __restrict__ A, const _Float16* __restrict__ W,
    const float* __restrict__ bias, float* __restrict__ C, int Kv, int N) {
    constexpr int KP = Ks * 32;
    constexpr int LDK = KP + 8;
    __shared__ __align__(16) _Float16 Al[64][LDK];
    __shared__ __align__(16) _Float16 Wl[64][LDK];

    const int tid = threadIdx.x;
    const int tt = blockIdx.x >> 1;
    const int boff = (blockIdx.x & 1) * 48;
    const int n0 = blockIdx.y * 64;
    constexpr int HP = KP / 2;

    for (int idx = tid; idx < 64 * HP; idx += 256) {
        int row = idx / HP;
        int k = (idx - row * HP) * 2;
        unsigned int va = 0, vw = 0;
        if (k < Kv) {
            va = *(const unsigned int*)(A + (size_t)(tt * 112 + boff + row) * Kv + k);
            vw = *(const unsigned int*)(W + (size_t)(n0 + row) * Kv + k);
        }
        *(unsigned int*)&Al[row][k] = va;
        *(unsigned int*)&Wl[row][k] = vw;
    }
    __syncthreads();

    const int w = tid >> 6, l = tid & 63, hi = l >> 4;
    half8 a[Ks];
    #pragma unroll
    for (int kk = 0; kk < Ks; ++kk)
        a[kk] = *(const half8*)&Al[w * 16 + (l & 15)][kk * 32 + hi * 8];

    f32x4 acc[4];
    #pragma unroll
    for (int jt = 0; jt < 4; ++jt) {
        acc[jt] = f32x4{0.f, 0.f, 0.f, 0.f};
        #pragma unroll
        for (int kk = 0; kk < Ks; ++kk) {
            half8 b = *(const half8*)&Wl[jt * 16 + (l & 15)][kk * 32 + hi * 8];
            acc[jt] = __builtin_amdgcn_mfma_f32_16x16x32_f16(a[kk], b, acc[jt], 0, 0, 0);
        }
    }

    const int bx = (boff >> 2) + w * 4 + hi;
    #pragma unroll
    for (int jt = 0; jt < 4; ++jt) {
        int n = n0 + jt * 16 + (l & 15);
        float bs = bias[n];
        f32x4 v = acc[jt];
        v[0] += bs; v[1] += bs; v[2] += bs; v[3] += bs;
        *(f32x4*)(C + ((size_t)(tt * 28 + bx) * N + n) * 4) = v;
    }
}

#define FTAIL                                                                 \
    __builtin_amdgcn_sched_barrier(0);                                        \
    asm volatile("s_waitcnt lgkmcnt(0)");                                     \
    __builtin_amdgcn_sched_barrier(0);                                        \
    __builtin_amdgcn_s_barrier();                                             \
    __builtin_amdgcn_sched_barrier(0);

#define PICK(A4) ((hi & 2) ? ((hi & 1) ? A4[3] : A4[2]) : ((hi & 1) ? A4[1] : A4[0]))

#define ACT(aI, aF, aG4, aO)                                                  \
    float gI = PICK(aI), gF = PICK(aF), gG = PICK(aG4), gO = PICK(aO);        \
    float si = sigmf(gI), sf = sigmf(gF), tg = tanhx(gG), so = sigmf(gO);     \
    float cn = sf * cst + si * tg;                                            \
    cst = cn;                                                                 \
    float hn = so * tanhx(cn);                                                \
    _Float16 hv = (_Float16)hn;

// ---------------------------------------------------------------------------
// Fused layer PAIR at H=128 for layers 0+1 (round-11 logic, which PASSED
// correctness; perf fix = __launch_bounds__(1024, 4): one 16-wave block is
// 4 waves/EU, so min-waves=4 raises the VGPR cap to 512/wave -> the B-role's
// ~190 live VGPRs (whh1+wih1 weights) no longer spill (round-11 showed the
// default heuristic picked 64 VGPR and scratch-thrashed).
// ---------------------------------------------------------------------------
template <int H>
__global__ __launch_bounds__(8 * H, 4) void lstm_pair(
    const float* __restrict__ xg,        // [75+3][28][4H][4] f32 (layer A)
    const _Float16* __restrict__ whhA,   // [4H][H]
    const _Float16* __restrict__ whhB,   // [4H][H]
    const _Float16* __restrict__ wihB,   // [4H][H] plain
    const float* __restrict__ biasB,     // [4H] plain
    _Float16* __restrict__ houtB) {      // [75][112][H]
    constexpr int Ks = H / 32;
    constexpr int NW = H / 16;
    constexpr int LDH = H + 8;
    constexpr int XSTR = 448 * H;
    constexpr int HSTR = 112 * H;

    __shared__ __align__(16) _Float16 hbA[2][4][LDH];
    __shared__ __align__(16) _Float16 hbB[2][4][LDH];
    __shared__ __align__(16) _Float16 hp[2][4][LDH];

    const int tid = threadIdx.x;
    const int w = tid >> 6, l = tid & 63, hi = l >> 4;
    const bool isA = (w < NW);
    const int wl = isA ? w : (w - NW);
    const int col = wl * 16 + (l & 15);
    const int blk = blockIdx.x;

    half8 bwA[4][Ks], bwB[4][Ks], bwI[4][Ks];
    float bI = 0.f, bF = 0.f, bG = 0.f, bO = 0.f;
    if (isA) {
        #pragma unroll
        for (int G = 0; G < 4; ++G)
            #pragma unroll
            for (int kk = 0; kk < Ks; ++kk)
                bwA[G][kk] = *(const half8*)(whhA + (size_t)(G * H + col) * H + kk * 32 + hi * 8);
    } else {
        #pragma unroll
        for (int G = 0; G < 4; ++G)
            #pragma unroll
            for (int kk = 0; kk < Ks; ++kk) {
                bwB[G][kk] = *(const half8*)(whhB + (size_t)(G * H + col) * H + kk * 32 + hi * 8);
                bwI[G][kk] = *(const half8*)(wihB + (size_t)(G * H + col) * H + kk * 32 + hi * 8);
            }
        bI = biasB[0 * H + col];
        bF = biasB[1 * H + col];
        bG = biasB[2 * H + col];
        bO = biasB[3 * H + col];
    }

    for (int i = tid; i < 2 * 4 * LDH; i += 8 * H) {
        ((_Float16*)hbA)[i] = (_Float16)0;
        ((_Float16*)hbB)[i] = (_Float16)0;
        ((_Float16*)hp)[i] = (_Float16)0;
    }
    __syncthreads();

    const float* xp = xg + (size_t)blk * (4 * H * 4) + col * 16;
    _Float16* hop = houtB + (size_t)(blk * 4 + hi) * H + col;

    f32x4 P0[4], P1[4], P2[4];
#define XLOADP(PA)                                                            \
    PA[0] = *(const f32x4*)(xp + 0);                                          \
    PA[1] = *(const f32x4*)(xp + 4);                                          \
    PA[2] = *(const f32x4*)(xp + 8);                                          \
    PA[3] = *(const f32x4*)(xp + 12);                                         \
    xp += XSTR;

    if (isA) {
        XLOADP(P0)
        XLOADP(P1)
        XLOADP(P2)
    }

    float cst = 0.f;

#define ASTEP(PA, CUR)                                                        \
    {                                                                         \
        half8 afr[Ks];                                                        \
        _Pragma("unroll") for (int kk = 0; kk < Ks; ++kk)                     \
            afr[kk] = *(const half8*)&hbA[CUR][(l & 15) & 3][kk * 32 + hi * 8]; \
        f32x4 aI = PA[0], aF = PA[1], aG4 = PA[2], aO = PA[3];                \
        XLOADP(PA)                                                            \
        _Pragma("unroll") for (int kk = 0; kk < Ks; ++kk) {                   \
            aI = __builtin_amdgcn_mfma_f32_16x16x32_f16(afr[kk], bwA[0][kk], aI, 0, 0, 0); \
            aF = __builtin_amdgcn_mfma_f32_16x16x32_f16(afr[kk], bwA[1][kk], aF, 0, 0, 0); \
            aG4 = __builtin_amdgcn_mfma_f32_16x16x32_f16(afr[kk], bwA[2][kk], aG4, 0, 0, 0); \
            aO = __builtin_amdgcn_mfma_f32_16x16x32_f16(afr[kk], bwA[3][kk], aO, 0, 0, 0); \
        }                                                                     \
        ACT(aI, aF, aG4, aO)                                                  \
        hbA[CUR ^ 1][hi][col] = hv;                                           \
        hp[CUR ^ 1][hi][col] = hv;                                            \
    }

#define BSTEP(CUR)                                                            \
    {                                                                         \
        half8 afr[Ks], air[Ks];                                               \
        _Pragma("unroll") for (int kk = 0; kk < Ks; ++kk) {                   \
            afr[kk] = *(const half8*)&hbB[CUR][(l & 15) & 3][kk * 32 + hi * 8]; \
            air[kk] = *(const half8*)&hp[CUR][(l & 15) & 3][kk * 32 + hi * 8]; \
        }                                                                     \
        f32x4 aI = {bI, bI, bI, bI}, aF = {bF, bF, bF, bF};                   \
        f32x4 aG4 = {bG, bG, bG, bG}, aO = {bO, bO, bO, bO};                  \
        _Pragma("unroll") for (int kk = 0; kk < Ks; ++kk) {                   \
            aI = __builtin_amdgcn_mfma_f32_16x16x32_f16(afr[kk], bwB[0][kk], aI, 0, 0, 0); \
            aF = __builtin_amdgcn_mfma_f32_16x16x32_f16(afr[kk], bwB[1][kk], aF, 0, 0, 0); \
            aG4 = __builtin_amdgcn_mfma_f32_16x16x32_f16(afr[kk], bwB[2][kk], aG4, 0, 0, 0); \
            aO = __builtin_amdgcn_mfma_f32_16x16x32_f16(afr[kk], bwB[3][kk], aO, 0, 0, 0); \
        }                                                                     \
        _Pragma("unroll") for (int kk = 0; kk < Ks; ++kk) {                   \
            aI = __builtin_amdgcn_mfma_f32_16x16x32_f16(air[kk], bwI[0][kk], aI, 0, 0, 0); \
            aF = __builtin_amdgcn_mfma_f32_16x16x32_f16(air[kk], bwI[1][kk], aF, 0, 0, 0); \
            aG4 = __builtin_amdgcn_mfma_f32_16x16x32_f16(air[kk], bwI[2][kk], aG4, 0, 0, 0); \
            aO = __builtin_amdgcn_mfma_f32_16x16x32_f16(air[kk], bwI[3][kk], aO, 0, 0, 0); \
        }                                                                     \
        ACT(aI, aF, aG4, aO)                                                  \
        hbB[CUR ^ 1][hi][col] = hv;                                           \
        *hop = hv;                                                            \
        hop += HSTR;                                                          \
    }

#define PSTEP(PA, CUR, S)                                                     \
    {                                                                         \
        if (isA) {                                                            \
            ASTEP(PA, CUR)                                                    \
        } else if ((S) > 0) {                                                 \
            BSTEP(CUR)                                                        \
        }                                                                     \
        FTAIL                                                                 \
    }

    #pragma unroll 1
    for (int it = 0; it < 12; ++it) {
        const int b6 = it * 6;
        PSTEP(P0, 0, b6 + 0) PSTEP(P1, 1, b6 + 1) PSTEP(P2, 0, b6 + 2)
        PSTEP(P0, 1, b6 + 3) PSTEP(P1, 0, b6 + 4) PSTEP(P2, 1, b6 + 5)
    }
    PSTEP(P0, 0, 72) PSTEP(P1, 1, 73) PSTEP(P2, 0, 74)
    {  // s = 75: B finishes t = 74
        if (!isA) { BSTEP(1) }
        FTAIL
    }
#undef PSTEP
#undef BSTEP
#undef ASTEP
#undef XLOADP
}

// ---------------------------------------------------------------------------
// Quad-fused layers 2,3,4,5 + fused final linear (round-12 proven,
// unchanged). 25 blocks x 832 threads (13 waves).
// ---------------------------------------------------------------------------
__global__ __launch_bounds__(832) void lstm_quad(
    const float* __restrict__ xg,        // [78][28][256][4] f32 (layer 2)
    const _Float16* __restrict__ whh2, const _Float16* __restrict__ whh3,
    const _Float16* __restrict__ wih3, const _Float16* __restrict__ whh4,
    const _Float16* __restrict__ wih4, const _Float16* __restrict__ whh5,
    const _Float16* __restrict__ wih5, const float* __restrict__ biasP,
    const _Float16* __restrict__ lwI,    // [75][4][16][32] fp16
    const float* __restrict__ lb,        // [60] f32
    float* __restrict__ outF) {          // [100][60] f32
    __shared__ __align__(16) _Float16 hb2[2][4][72], hp2[2][4][72];
    __shared__ __align__(16) _Float16 hb3[2][4][72], hp3[2][4][72];
    __shared__ __align__(16) _Float16 hb4[2][4][40], hp4[2][4][40];
    __shared__ __align__(16) _Float16 hb5[2][4][40];

    const int tid = threadIdx.x;
    const int w = tid >> 6, l = tid & 63, hi = l >> 4;
    const int lr = (l & 15) & 3;
    const int blk = blockIdx.x;

    for (int i = tid; i < 2 * 4 * 72; i += 832) {
        ((_Float16*)hb2)[i] = (_Float16)0; ((_Float16*)hp2)[i] = (_Float16)0;
        ((_Float16*)hb3)[i] = (_Float16)0; ((_Float16*)hp3)[i] = (_Float16)0;
    }
    for (int i = tid; i < 2 * 4 * 40; i += 832) {
        ((_Float16*)hb4)[i] = (_Float16)0; ((_Float16*)hp4)[i] = (_Float16)0;
        ((_Float16*)hb5)[i] = (_Float16)0;
    }
    __syncthreads();

    float cst = 0.f;

    if (w < 4) {  // ----- L2: xg C-init role -----
        const int col = w * 16 + (l & 15);
        half8 bw[4][2];
        #pragma unroll
        for (int G = 0; G < 4; ++G)
            #pragma unroll
            for (int kk = 0; kk < 2; ++kk)
                bw[G][kk] = *(const half8*)(whh2 + (size_t)(G * 64 + col) * 64 + kk * 32 + hi * 8);
        const float* xp = xg + (size_t)blk * 1024 + col * 16;
        f32x4 P0[4], P1[4], P2[4];
#define XLOADQ(PA)                                                            \
        PA[0] = *(const f32x4*)(xp + 0);                                      \
        PA[1] = *(const f32x4*)(xp + 4);                                      \
        PA[2] = *(const f32x4*)(xp + 8);                                      \
        PA[3] = *(const f32x4*)(xp + 12);                                     \
        xp += 28672;
        XLOADQ(P0)
        XLOADQ(P1)
        XLOADQ(P2)

#define QA(PA, CUR, S)                                                        \
        {                                                                     \
            if ((S) < 75) {                                                   \
                half8 afr[2];                                                 \
                _Pragma("unroll") for (int kk = 0; kk < 2; ++kk)              \
                    afr[kk] = *(const half8*)&hb2[CUR][lr][kk * 32 + hi * 8]; \
                f32x4 aI = PA[0], aF = PA[1], aG4 = PA[2], aO = PA[3];        \
                XLOADQ(PA)                                                    \
                _Pragma("unroll") for (int kk = 0; kk < 2; ++kk) {            \
                    aI = __builtin_amdgcn_mfma_f32_16x16x32_f16(afr[kk], bw[0][kk], aI, 0, 0, 0);  \
                    aF = __builtin_amdgcn_mfma_f32_16x16x32_f16(afr[kk], bw[1][kk], aF, 0, 0, 0);  \
                    aG4 = __builtin_amdgcn_mfma_f32_16x16x32_f16(afr[kk], bw[2][kk], aG4, 0, 0, 0);\
                    aO = __builtin_amdgcn_mfma_f32_16x16x32_f16(afr[kk], bw[3][kk], aO, 0, 0, 0);  \
                }                                                             \
                ACT(aI, aF, aG4, aO)                                          \
                hb2[(CUR) ^ 1][hi][col] = hv;                                 \
                hp2[(CUR) ^ 1][hi][col] = hv;                                 \
            }                                                                 \
            FTAIL                                                             \
        }
        #pragma unroll 1
        for (int it = 0; it < 13; ++it) {
            const int b6 = it * 6;
            QA(P0, 0, b6 + 0) QA(P1, 1, b6 + 1) QA(P2, 0, b6 + 2)
            QA(P0, 1, b6 + 3) QA(P1, 0, b6 + 4) QA(P2, 1, b6 + 5)
        }
#undef QA
#undef XLOADQ
    } else if (w < 8) {  // ----- L3: H=64, HIN=64, lag 1 -----
        const int col = (w - 4) * 16 + (l & 15);
        half8 bwB[4][2], bwI[4][2];
        #pragma unroll
        for (int G = 0; G < 4; ++G)
            #pragma unroll
            for (int kk = 0; kk < 2; ++kk) {
                bwB[G][kk] = *(const half8*)(whh3 + (size_t)(G * 64 + col) * 64 + kk * 32 + hi * 8);
                bwI[G][kk] = *(const half8*)(wih3 + (size_t)(G * 64 + col) * 64 + kk * 32 + hi * 8);
            }
        const float bI = biasP[col], bF = biasP[64 + col];
        const float bG = biasP[128 + col], bO = biasP[192 + col];
        #pragma unroll 1
        for (int s = 0; s < 78; ++s) {
            const int cur = s & 1;
            if (s >= 1 && s <= 75) {
                half8 afr[2], air[2];
                #pragma unroll
                for (int kk = 0; kk < 2; ++kk) {
                    afr[kk] = *(const half8*)&hb3[cur][lr][kk * 32 + hi * 8];
                    air[kk] = *(const half8*)&hp2[cur][lr][kk * 32 + hi * 8];
                }
                f32x4 aI = {bI, bI, bI, bI}, aF = {bF, bF, bF, bF};
                f32x4 aG4 = {bG, bG, bG, bG}, aO = {bO, bO, bO, bO};
                #pragma unroll
                for (int kk = 0; kk < 2; ++kk) {
                    aI = __builtin_amdgcn_mfma_f32_16x16x32_f16(afr[kk], bwB[0][kk], aI, 0, 0, 0);
                    aF = __builtin_amdgcn_mfma_f32_16x16x32_f16(afr[kk], bwB[1][kk], aF, 0, 0, 0);
                    aG4 = __builtin_amdgcn_mfma_f32_16x16x32_f16(afr[kk], bwB[2][kk], aG4, 0, 0, 0);
                    aO = __builtin_amdgcn_mfma_f32_16x16x32_f16(afr[kk], bwB[3][kk], aO, 0, 0, 0);
                }
                #pragma unroll
                for (int kk = 0; kk < 2; ++kk) {
                    aI = __builtin_amdgcn_mfma_f32_16x16x32_f16(air[kk], bwI[0][kk], aI, 0, 0, 0);
                    aF = __builtin_amdgcn_mfma_f32_16x16x32_f16(air[kk], bwI[1][kk], aF, 0, 0, 0);
                    aG4 = __builtin_amdgcn_mfma_f32_16x16x32_f16(air[kk], bwI[2][kk], aG4, 0, 0, 0);
                    aO = __builtin_amdgcn_mfma_f32_16x16x32_f16(air[kk], bwI[3][kk], aO, 0, 0, 0);
                }
                ACT(aI, aF, aG4, aO)
                hb3[cur ^ 1][hi][col] = hv;
                hp3[cur ^ 1][hi][col] = hv;
            }
            FTAIL
        }
    } else if (w < 10) {  // ----- L4: H=32, HIN=64, lag 2 -----
        const int col = (w - 8) * 16 + (l & 15);
        half8 bwB[4], bwI[4][2];
        #pragma unroll
        for (int G = 0; G < 4; ++G) {
            bwB[G] = *(const half8*)(whh4 + (size_t)(G * 32 + col) * 32 + hi * 8);
            #pragma unroll
            for (int kk = 0; kk < 2; ++kk)
                bwI[G][kk] = *(const half8*)(wih4 + (size_t)(G * 32 + col) * 64 + kk * 32 + hi * 8);
        }
        const float* bp = biasP + 256;
        const float bI = bp[col], bF = bp[32 + col], bG = bp[64 + col], bO = bp[96 + col];
        #pragma unroll 1
        for (int s = 0; s < 78; ++s) {
            const int cur = s & 1;
            if (s >= 2 && s <= 76) {
                half8 afr = *(const half8*)&hb4[cur][lr][hi * 8];
                half8 air[2];
                #pragma unroll
                for (int kk = 0; kk < 2; ++kk)
                    air[kk] = *(const half8*)&hp3[cur][lr][kk * 32 + hi * 8];
                f32x4 aI = {bI, bI, bI, bI}, aF = {bF, bF, bF, bF};
                f32x4 aG4 = {bG, bG, bG, bG}, aO = {bO, bO, bO, bO};
                aI = __builtin_amdgcn_mfma_f32_16x16x32_f16(afr, bwB[0], aI, 0, 0, 0);
                aF = __builtin_amdgcn_mfma_f32_16x16x32_f16(afr, bwB[1], aF, 0, 0, 0);
                aG4 = __builtin_amdgcn_mfma_f32_16x16x32_f16(afr, bwB[2], aG4, 0, 0, 0);
                aO = __builtin_amdgcn_mfma_f32_16x16x32_f16(afr, bwB[3], aO, 0, 0, 0);
                #pragma unroll
                for (int kk = 0; kk < 2; ++kk) {
                    aI = __builtin_amdgcn_mfma_f32_16x16x32_f16(air[kk], bwI[0][kk], aI, 0, 0, 0);
                    aF = __builtin_amdgcn_mfma_f32_16x16x32_f16(air[kk], bwI[1][kk], aF, 0, 0, 0);
                    aG4 = __builtin_amdgcn_mfma_f32_16x16x32_f16(air[kk], bwI[2][kk], aG4, 0, 0, 0);
                    aO = __builtin_amdgcn_mfma_f32_16x16x32_f16(air[kk], bwI[3][kk], aO, 0, 0, 0);
                }
                ACT(aI, aF, aG4, aO)
                hb4[cur ^ 1][hi][col] = hv;
                hp4[cur ^ 1][hi][col] = hv;
            }
            FTAIL
        }
    } else if (w < 12) {  // ----- L5: H=32, HIN=32, lag 3; publishes hb5 -----
        const int col = (w - 10) * 16 + (l & 15);
        half8 bwB[4], bwI[4];
        #pragma unroll
        for (int G = 0; G < 4; ++G) {
            bwB[G] = *(const half8*)(whh5 + (size_t)(G * 32 + col) * 32 + hi * 8);
            bwI[G] = *(const half8*)(wih5 + (size_t)(G * 32 + col) * 32 + hi * 8);
        }
        const float* bp = biasP + 384;
        const float bI = bp[col], bF = bp[32 + col], bG = bp[64 + col], bO = bp[96 + col];
        #pragma unroll 1
        for (int s = 0; s < 78; ++s) {
            const int cur = s & 1;
            if (s >= 3) {
                half8 afr = *(const half8*)&hb5[cur][lr][hi * 8];
                half8 air = *(const half8*)&hp4[cur][lr][hi * 8];
                f32x4 aI = {bI, bI, bI, bI}, aF = {bF, bF, bF, bF};
                f32x4 aG4 = {bG, bG, bG, bG}, aO = {bO, bO, bO, bO};
                aI = __builtin_amdgcn_mfma_f32_16x16x32_f16(afr, bwB[0], aI, 0, 0, 0);
                aF = __builtin_amdgcn_mfma_f32_16x16x32_f16(afr, bwB[1], aF, 0, 0, 0);
                aG4 = __builtin_amdgcn_mfma_f32_16x16x32_f16(afr, bwB[2], aG4, 0, 0, 0);
                aO = __builtin_amdgcn_mfma_f32_16x16x32_f16(afr, bwB[3], aO, 0, 0, 0);
                aI = __builtin_amdgcn_mfma_f32_16x16x32_f16(air, bwI[0], aI, 0, 0, 0);
                aF = __builtin_amdgcn_mfma_f32_16x16x32_f16(air, bwI[1], aF, 0, 0, 0);
                aG4 = __builtin_amdgcn_mfma_f32_16x16x32_f16(air, bwI[2], aG4, 0, 0, 0);
                aO = __builtin_amdgcn_mfma_f32_16x16x32_f16(air, bwI[3], aO, 0, 0, 0);
                ACT(aI, aF, aG4, aO)
                hb5[cur ^ 1][hi][col] = hv;
            }
            FTAIL
        }
    } else {  // ----- LIN: lag 4; out[b][o] += lw[o][t*32+hc]*h5_t[b][hc] -----
        const int ln = l & 15;
        const _Float16* lwp = lwI + (size_t)ln * 32 + hi * 8;
        half8 LA[4], LB[4];
        #pragma unroll
        for (int tl = 0; tl < 4; ++tl) {
            LA[tl] = *(const half8*)(lwp + (size_t)(0 * 4 + tl) * 512);
            LB[tl] = *(const half8*)(lwp + (size_t)(1 * 4 + tl) * 512);
        }
        f32x4 acc[4];
        #pragma unroll
        for (int tl = 0; tl < 4; ++tl) acc[tl] = f32x4{0.f, 0.f, 0.f, 0.f};

        #pragma unroll 1
        for (int it = 0; it < 39; ++it) {
            {  // even step s0 = 2*it, t = s0 - 4, reads hb5[0], uses LA
                int t = 2 * it - 4;
                if (t >= 0) {
                    half8 hf = *(const half8*)&hb5[0][lr][hi * 8];
                    #pragma unroll
                    for (int tl = 0; tl < 4; ++tl)
                        acc[tl] = __builtin_amdgcn_mfma_f32_16x16x32_f16(LA[tl], hf, acc[tl], 0, 0, 0);
                }
                int tn = t + 2;
                if (tn < 0) tn = 0;
                if (tn > 74) tn = 74;
                #pragma unroll
                for (int tl = 0; tl < 4; ++tl)
                    LA[tl] = *(const half8*)(lwp + ((size_t)tn * 4 + tl) * 512);
                FTAIL
            }
            {  // odd step s1 = 2*it+1, t = s1 - 4, reads hb5[1], uses LB
                int t = 2 * it - 3;
                if (t >= 0) {
                    half8 hf = *(const half8*)&hb5[1][lr][hi * 8];
                    #pragma unroll
                    for (int tl = 0; tl < 4; ++tl)
                        acc[tl] = __builtin_amdgcn_mfma_f32_16x16x32_f16(LB[tl], hf, acc[tl], 0, 0, 0);
                }
                int tn = t + 2;
                if (tn < 0) tn = 0;
                if (tn > 74) tn = 74;
                #pragma unroll
                for (int tl = 0; tl < 4; ++tl)
                    LB[tl] = *(const half8*)(lwp + ((size_t)tn * 4 + tl) * 512);
                FTAIL
            }
        }
        // post-loop: t = 74 (written by L5 at s=77 into hb5[0]; final barrier done)
        {
            half8 hf = *(const half8*)&hb5[0][lr][hi * 8];
            #pragma unroll
            for (int tl = 0; tl < 4; ++tl)
                acc[tl] = __builtin_amdgcn_mfma_f32_16x16x32_f16(LA[tl], hf, acc[tl], 0, 0, 0);
        }
        if (ln < 4) {
            int b = blk * 4 + ln;
            #pragma unroll
            for (int tl = 0; tl < 4; ++tl)
                #pragma unroll
                for (int r = 0; r < 4; ++r) {
                    int o = tl * 16 + hi * 4 + r;
                    if (o < 60) outF[b * 60 + o] = acc[tl][r] + lb[o];
                }
        }
    }
}

// ---------------------------------------------------------------------------
extern "C" void kernel_launch(void* const* d_in, const int* in_sizes, int n_in,
                              void* d_out, int out_size, void* d_ws, size_t ws_size,
                              hipStream_t stream) {
    const float* x = (const float*)d_in[0];
    const float* wih[6];
    const float* whhp[6];
    const float* bih[6];
    const float* bhh[6];
    for (int i = 0; i < 6; ++i) {
        wih[i] = (const float*)d_in[1 + 4 * i];
        whhp[i] = (const float*)d_in[2 + 4 * i];
        bih[i] = (const float*)d_in[3 + 4 * i];
        bhh[i] = (const float*)d_in[4 + 4 * i];
    }
    const float* lw = (const float*)d_in[25];
    const float* lb = (const float*)d_in[26];
    float* out = (float*)d_out;

    char* ws = (char*)d_ws;
    size_t cur = 0;
    auto alloc = [&](size_t b) {
        size_t o = cur;
        cur += (b + 255) & ~(size_t)255;
        return o;
    };
    _Float16* wihI0 = (_Float16*)(ws + alloc(38912 * 2));
    _Float16* wihP1 = (_Float16*)(ws + alloc(65536 * 2));
    _Float16* wihI2 = (_Float16*)(ws + alloc(32768 * 2));
    _Float16* wihP3 = (_Float16*)(ws + alloc(16384 * 2));
    _Float16* wihP4 = (_Float16*)(ws + alloc(8192 * 2));
    _Float16* wihP5 = (_Float16*)(ws + alloc(4096 * 2));
    _Float16* whhP[6];
    const size_t whhBytes[6] = {131072, 131072, 32768, 32768, 8192, 8192};
    for (int i = 0; i < 6; ++i) whhP[i] = (_Float16*)(ws + alloc(whhBytes[i]));
    _Float16* lwI = (_Float16*)(ws + alloc(153600 * 2));
    float* biasI = (float*)(ws + alloc(768 * 4));
    float* biasP = (float*)(ws + alloc(1024 * 4));
    float* xg = (float*)(ws + alloc((size_t)78 * 28 * 512 * 4 * 4));
    _Float16* h1 = (_Float16*)(ws + alloc((size_t)75 * 112 * 128 * 2));

    PrepPtrs pp;
    for (int i = 0; i < 6; ++i) {
        pp.wih[i] = wih[i];
        pp.whh[i] = whhp[i];
        pp.bi[i] = bih[i];
        pp.bh[i] = bhh[i];
        pp.whhP[i] = whhP[i];
    }
    pp.lw = lw;
    pp.wihI0 = wihI0;
    pp.wihP1 = wihP1;
    pp.wihI2 = wihI2;
    pp.wihP3 = wihP3;
    pp.wihP4 = wihP4;
    pp.wihP5 = wihP5;
    pp.biasI = biasI;
    pp.biasP = biasP;
    pp.lwI = lwI;
    prep_kernel<<<1927, 256, 0, stream>>>(pp);

    // layer 0 xg GEMM straight from f32 x, then pair-fused layers 0+1
    gemm_xg0<<<dim3(150, 8), 256, 0, stream>>>(x, wihI0, biasI + 0, xg);
    lstm_pair<128><<<25, 1024, 0, stream>>>(xg, whhP[0], whhP[1], wihP1,
                                            biasP + 512, h1);
    // layer 2 xg GEMM (I=128, H=64), then quad-fused layers 2..5 + linear
    gemm_xg<4><<<dim3(150, 4), 256, 0, stream>>>(h1, wihI2, biasI + 512, xg, 128, 256);
    lstm_quad<<<25, 832, 0, stream>>>(xg, whhP[2], whhP[3], wihP3, whhP[4],
                                      wihP4, whhP[5], wihP5, biasP, lwI, lb, out);
}

// Round 14
// 211.999 us; speedup vs baseline: 4.1720x; 4.1720x over previous
//
#include <hip/hip_runtime.h>

using half8 = __attribute__((ext_vector_type(8))) _Float16;
using f32x4 = __attribute__((ext_vector_type(4))) float;

__device__ __forceinline__ float sigmf(float x) {
    return __builtin_amdgcn_rcpf(1.0f + __expf(-x));
}
__device__ __forceinline__ float tanhx(float x) {
    return 1.0f - 2.0f * __builtin_amdgcn_rcpf(1.0f + __expf(x + x));
}
// load 8 consecutive f32 and convert to half8 (32B-aligned sources)
__device__ __forceinline__ half8 cvt8(const float* p) {
    f32x4 a = *(const f32x4*)p;
    f32x4 b = *(const f32x4*)(p + 4);
    half8 r;
    r[0] = (_Float16)a[0]; r[1] = (_Float16)a[1];
    r[2] = (_Float16)a[2]; r[3] = (_Float16)a[3];
    r[4] = (_Float16)b[0]; r[5] = (_Float16)b[1];
    r[6] = (_Float16)b[2]; r[7] = (_Float16)b[3];
    return r;
}

// ---------------------------------------------------------------------------
// Prep: ONLY lwI = lin_w as [75][4][16][32] fp16 (all weight conversion now
// happens inside the consumer kernels).
// ---------------------------------------------------------------------------
__global__ __launch_bounds__(256) void prep_lw(const float* __restrict__ lw,
                                               _Float16* __restrict__ lwI) {
    int i = blockIdx.x * 256 + threadIdx.x;
    if (i >= 153600) return;
    int t = i >> 11;
    int rem = i & 2047;
    int tile = rem >> 9, op = (rem >> 5) & 15, hc = rem & 31;
    int o = tile * 16 + op;
    float v = (o < 60) ? lw[(size_t)o * 2400 + t * 32 + hc] : 0.0f;
    lwI[i] = (_Float16)v;
}

// ---------------------------------------------------------------------------
// Layer-0 xg GEMM: reads f32 x AND f32 wih0 directly (converts during LDS
// staging; W rows interleaved on the fly: n -> src (n&3)*128+(n>>2)).
// Output layout [75][28][512][4] f32 (round-7 proven fragment layout).
// ---------------------------------------------------------------------------
__global__ __launch_bounds__(256) void gemm_xg0(
    const float* __restrict__ X,        // [100][75][75] f32
    const float* __restrict__ W0,       // wih0 [512][75] f32
    const float* __restrict__ bi0, const float* __restrict__ bh0,
    float* __restrict__ C) {
    constexpr int Ks = 3, LDK = 104, HP = 48, N = 512;
    __shared__ __align__(16) _Float16 Al[64][LDK];
    __shared__ __align__(16) _Float16 Wl[64][LDK];

    const int tid = threadIdx.x;
    const int tt = blockIdx.x >> 1;
    const int boff = (blockIdx.x & 1) * 48;
    const int n0 = blockIdx.y * 64;

    for (int idx = tid; idx < 64 * HP; idx += 256) {
        int row = idx / HP;
        int k = (idx - row * HP) * 2;
        unsigned int va = 0, vw = 0;
        int b = boff + row;
        if (b < 100 && k < 75) {
            float f0 = X[((size_t)b * 75 + tt) * 75 + k];
            float f1 = (k + 1 < 75) ? X[((size_t)b * 75 + tt) * 75 + k + 1] : 0.0f;
            _Float16 h2[2] = {(_Float16)f0, (_Float16)f1};
            va = *(unsigned int*)h2;
        }
        if (k < 75) {
            int n = n0 + row;
            int src = (n & 3) * 128 + (n >> 2);
            float f0 = W0[(size_t)src * 75 + k];
            float f1 = (k + 1 < 75) ? W0[(size_t)src * 75 + k + 1] : 0.0f;
            _Float16 h2[2] = {(_Float16)f0, (_Float16)f1};
            vw = *(unsigned int*)h2;
        }
        *(unsigned int*)&Al[row][k] = va;
        *(unsigned int*)&Wl[row][k] = vw;
    }
    __syncthreads();

    const int w = tid >> 6, l = tid & 63, hi = l >> 4;
    half8 a[Ks];
    #pragma unroll
    for (int kk = 0; kk < Ks; ++kk)
        a[kk] = *(const half8*)&Al[w * 16 + (l & 15)][kk * 32 + hi * 8];

    f32x4 acc[4];
    #pragma unroll
    for (int jt = 0; jt < 4; ++jt) {
        acc[jt] = f32x4{0.f, 0.f, 0.f, 0.f};
        #pragma unroll
        for (int kk = 0; kk < Ks; ++kk) {
            half8 b = *(const half8*)&Wl[jt * 16 + (l & 15)][kk * 32 + hi * 8];
            acc[jt] = __builtin_amdgcn_mfma_f32_16x16x32_f16(a[kk], b, acc[jt], 0, 0, 0);
        }
    }

    const int bx = (boff >> 2) + w * 4 + hi;
    #pragma unroll
    for (int jt = 0; jt < 4; ++jt) {
        int n = n0 + jt * 16 + (l & 15);
        int src = (n & 3) * 128 + (n >> 2);
        float bs = bi0[src] + bh0[src];
        f32x4 v = acc[jt];
        v[0] += bs; v[1] += bs; v[2] += bs; v[3] += bs;
        *(f32x4*)(C + ((size_t)(tt * 28 + bx) * N + n) * 4) = v;
    }
}

// ---------------------------------------------------------------------------
// Layer-1 xg GEMM: A = h0 fp16, W = f32 wih1 (interleaved on load).
// ---------------------------------------------------------------------------
__global__ __launch_bounds__(256) void gemm_xg1(
    const _Float16* __restrict__ A,     // h0 [75][112][128] fp16
    const float* __restrict__ W1,       // wih1 [512][128] f32
    const float* __restrict__ bi1, const float* __restrict__ bh1,
    float* __restrict__ C) {
    constexpr int Ks = 4, LDK = 136, HP = 64, Kv = 128, N = 512;
    __shared__ __align__(16) _Float16 Al[64][LDK];
    __shared__ __align__(16) _Float16 Wl[64][LDK];

    const int tid = threadIdx.x;
    const int tt = blockIdx.x >> 1;
    const int boff = (blockIdx.x & 1) * 48;
    const int n0 = blockIdx.y * 64;

    for (int idx = tid; idx < 64 * HP; idx += 256) {
        int row = idx / HP;
        int k = (idx - row * HP) * 2;
        unsigned int va = *(const unsigned int*)(A + (size_t)(tt * 112 + boff + row) * Kv + k);
        int n = n0 + row;
        int src = (n & 3) * 128 + (n >> 2);
        float f0 = W1[(size_t)src * 128 + k];
        float f1 = W1[(size_t)src * 128 + k + 1];
        _Float16 h2[2] = {(_Float16)f0, (_Float16)f1};
        *(unsigned int*)&Al[row][k] = va;
        *(unsigned int*)&Wl[row][k] = *(unsigned int*)h2;
    }
    __syncthreads();

    const int w = tid >> 6, l = tid & 63, hi = l >> 4;
    half8 a[Ks];
    #pragma unroll
    for (int kk = 0; kk < Ks; ++kk)
        a[kk] = *(const half8*)&Al[w * 16 + (l & 15)][kk * 32 + hi * 8];

    f32x4 acc[4];
    #pragma unroll
    for (int jt = 0; jt < 4; ++jt) {
        acc[jt] = f32x4{0.f, 0.f, 0.f, 0.f};
        #pragma unroll
        for (int kk = 0; kk < Ks; ++kk) {
            half8 b = *(const half8*)&Wl[jt * 16 + (l & 15)][kk * 32 + hi * 8];
            acc[jt] = __builtin_amdgcn_mfma_f32_16x16x32_f16(a[kk], b, acc[jt], 0, 0, 0);
        }
    }

    const int bx = (boff >> 2) + w * 4 + hi;
    #pragma unroll
    for (int jt = 0; jt < 4; ++jt) {
        int n = n0 + jt * 16 + (l & 15);
        int src = (n & 3) * 128 + (n >> 2);
        float bs = bi1[src] + bh1[src];
        f32x4 v = acc[jt];
        v[0] += bs; v[1] += bs; v[2] += bs; v[3] += bs;
        *(f32x4*)(C + ((size_t)(tt * 28 + bx) * N + n) * 4) = v;
    }
}

#define FTAIL                                                                 \
    __builtin_amdgcn_sched_barrier(0);                                        \
    asm volatile("s_waitcnt lgkmcnt(0)");                                     \
    __builtin_amdgcn_sched_barrier(0);                                        \
    __builtin_amdgcn_s_barrier();                                             \
    __builtin_amdgcn_sched_barrier(0);

#define PICK(A4) ((hi & 2) ? ((hi & 1) ? A4[3] : A4[2]) : ((hi & 1) ? A4[1] : A4[0]))

#define ACT(aI, aF, aG4, aO)                                                  \
    float gI = PICK(aI), gF = PICK(aF), gG = PICK(aG4), gO = PICK(aO);        \
    float si = sigmf(gI), sf = sigmf(gF), tg = tanhx(gG), so = sigmf(gO);     \
    float cn = sf * cst + si * tg;                                            \
    cst = cn;                                                                 \
    float hn = so * tanhx(cn);                                                \
    _Float16 hv = (_Float16)hn;

// ---------------------------------------------------------------------------
// Layer-0 recurrence (round-7 proven structure; LDH 136->160 for uniform
// 2-way bank aliasing (free, m136); whh converted from f32 at init).
// ---------------------------------------------------------------------------
__global__ __launch_bounds__(512) void lstm_rec0(
    const float* __restrict__ xg,       // [78][28][512][4] f32
    const float* __restrict__ whhf,     // whh0 [512][128] f32
    _Float16* __restrict__ hout) {      // [75][112][128] fp16
    constexpr int H = 128, Ks = 4, LDH = 160;
    constexpr int XSTR = 448 * H;
    constexpr int HSTR = 112 * H;

    __shared__ __align__(16) _Float16 hbuf[2][4][LDH];

    const int tid = threadIdx.x;
    const int w = tid >> 6, l = tid & 63, hi = l >> 4;
    const int col = w * 16 + (l & 15);
    const int blk = blockIdx.x;

    half8 bw[4][Ks];
    #pragma unroll
    for (int G = 0; G < 4; ++G)
        #pragma unroll
        for (int kk = 0; kk < Ks; ++kk)
            bw[G][kk] = cvt8(whhf + (size_t)(G * H + col) * H + kk * 32 + hi * 8);

    for (int i = tid; i < 2 * 4 * LDH; i += 512) ((_Float16*)hbuf)[i] = (_Float16)0;
    __syncthreads();

    const float* xp = xg + (size_t)blk * (4 * H * 4) + col * 16;
    _Float16* hop = hout + (size_t)(blk * 4 + hi) * H + col;

    f32x4 P0[4], P1[4], P2[4];
#define XLOAD(PA)                                                             \
    PA[0] = *(const f32x4*)(xp + 0);                                          \
    PA[1] = *(const f32x4*)(xp + 4);                                          \
    PA[2] = *(const f32x4*)(xp + 8);                                          \
    PA[3] = *(const f32x4*)(xp + 12);                                         \
    xp += XSTR;

    XLOAD(P0)
    XLOAD(P1)
    XLOAD(P2)

    float cst = 0.f;

#define LSTM_STEP(PA, CUR)                                                    \
    {                                                                         \
        half8 afr[Ks];                                                        \
        _Pragma("unroll") for (int kk = 0; kk < Ks; ++kk)                     \
            afr[kk] = *(const half8*)&hbuf[CUR][(l & 15) & 3][kk * 32 + hi * 8]; \
        f32x4 aI = PA[0], aF = PA[1], aG4 = PA[2], aO = PA[3];                \
        XLOAD(PA)                                                             \
        _Pragma("unroll") for (int kk = 0; kk < Ks; ++kk) {                   \
            aI = __builtin_amdgcn_mfma_f32_16x16x32_f16(afr[kk], bw[0][kk], aI, 0, 0, 0);  \
            aF = __builtin_amdgcn_mfma_f32_16x16x32_f16(afr[kk], bw[1][kk], aF, 0, 0, 0);  \
            aG4 = __builtin_amdgcn_mfma_f32_16x16x32_f16(afr[kk], bw[2][kk], aG4, 0, 0, 0);\
            aO = __builtin_amdgcn_mfma_f32_16x16x32_f16(afr[kk], bw[3][kk], aO, 0, 0, 0);  \
        }                                                                     \
        ACT(aI, aF, aG4, aO)                                                  \
        hbuf[CUR ^ 1][hi][col] = hv;                                          \
        *hop = hv;                                                            \
        hop += HSTR;                                                          \
        FTAIL                                                                 \
    }

    #pragma unroll 1
    for (int it = 0; it < 12; ++it) {
        LSTM_STEP(P0, 0) LSTM_STEP(P1, 1) LSTM_STEP(P2, 0)
        LSTM_STEP(P0, 1) LSTM_STEP(P1, 0) LSTM_STEP(P2, 1)
    }
    LSTM_STEP(P0, 0) LSTM_STEP(P1, 1) LSTM_STEP(P2, 0)
#undef LSTM_STEP
#undef XLOAD
}

// ---------------------------------------------------------------------------
// rec1xg: 25 blocks x 768 threads (12 waves). Waves 0-7 = L1 recurrence
// (xg1 C-init, 2-deep P prefetch, publishes h1 into LDS pipe hp; no global
// h writes). Waves 8-11 = xg2-on-the-fly: xg2[t] = wih2 * h1[t] + b2,
// consuming hp at lag 1, written in quad-L2's [t][blk][col*16+G*4+bs]
// layout. 76 steps, one barrier each; deletes the gemm2 dispatch.
// Per-role live VGPR ~140 / ~90; 12 waves = 3 waves/SIMD -> cap ~170.
// ---------------------------------------------------------------------------
__global__ __launch_bounds__(768) void rec1xg(
    const float* __restrict__ xg1,      // [78][28][512][4] f32
    const float* __restrict__ whh1f,    // whh1 [512][128] f32
    const float* __restrict__ wih2f,    // wih2 [256][128] f32
    const float* __restrict__ bi2, const float* __restrict__ bh2,
    float* __restrict__ xg2) {          // [78][28][256][4] f32
    constexpr int H = 128, Ks = 4, LDH = 160;
    constexpr int XSTR = 448 * H;

    __shared__ __align__(16) _Float16 hb1[2][4][LDH];
    __shared__ __align__(16) _Float16 hp[2][4][LDH];

    const int tid = threadIdx.x;
    const int w = tid >> 6, l = tid & 63, hi = l >> 4;
    const int lr = (l & 15) & 3;
    const int blk = blockIdx.x;

    for (int i = tid; i < 2 * 4 * LDH; i += 768) {
        ((_Float16*)hb1)[i] = (_Float16)0;
        ((_Float16*)hp)[i] = (_Float16)0;
    }
    __syncthreads();

    float cst = 0.f;

    if (w < 8) {  // ----- A: layer-1 recurrence -----
        const int col = w * 16 + (l & 15);
        half8 bw[4][Ks];
        #pragma unroll
        for (int G = 0; G < 4; ++G)
            #pragma unroll
            for (int kk = 0; kk < Ks; ++kk)
                bw[G][kk] = cvt8(whh1f + (size_t)(G * H + col) * H + kk * 32 + hi * 8);

        const float* xp = xg1 + (size_t)blk * (4 * H * 4) + col * 16;
        f32x4 P0[4], P1[4];
#define XLOADA(PA)                                                            \
        PA[0] = *(const f32x4*)(xp + 0);                                      \
        PA[1] = *(const f32x4*)(xp + 4);                                      \
        PA[2] = *(const f32x4*)(xp + 8);                                      \
        PA[3] = *(const f32x4*)(xp + 12);                                     \
        xp += XSTR;
        XLOADA(P0)
        XLOADA(P1)

#define ASTEP(PA, CUR)                                                        \
        {                                                                     \
            half8 afr[Ks];                                                    \
            _Pragma("unroll") for (int kk = 0; kk < Ks; ++kk)                 \
                afr[kk] = *(const half8*)&hb1[CUR][lr][kk * 32 + hi * 8];     \
            f32x4 aI = PA[0], aF = PA[1], aG4 = PA[2], aO = PA[3];            \
            XLOADA(PA)                                                        \
            _Pragma("unroll") for (int kk = 0; kk < Ks; ++kk) {               \
                aI = __builtin_amdgcn_mfma_f32_16x16x32_f16(afr[kk], bw[0][kk], aI, 0, 0, 0);  \
                aF = __builtin_amdgcn_mfma_f32_16x16x32_f16(afr[kk], bw[1][kk], aF, 0, 0, 0);  \
                aG4 = __builtin_amdgcn_mfma_f32_16x16x32_f16(afr[kk], bw[2][kk], aG4, 0, 0, 0);\
                aO = __builtin_amdgcn_mfma_f32_16x16x32_f16(afr[kk], bw[3][kk], aO, 0, 0, 0);  \
            }                                                                 \
            ACT(aI, aF, aG4, aO)                                              \
            hb1[(CUR) ^ 1][hi][col] = hv;                                     \
            hp[(CUR) ^ 1][hi][col] = hv;                                      \
        }

        #pragma unroll 1
        for (int it = 0; it < 38; ++it) {
            ASTEP(P0, 0)                // s = 2it (always < 75)
            FTAIL
            if (2 * it + 1 < 75) { ASTEP(P1, 1) }  // s = 2it+1
            FTAIL
        }
#undef ASTEP
#undef XLOADA
    } else {  // ----- B: xg2 = wih2 * h1 + b2, lag 1 -----
        const int col = (w - 8) * 16 + (l & 15);
        half8 bwI[4][Ks];
        #pragma unroll
        for (int G = 0; G < 4; ++G)
            #pragma unroll
            for (int kk = 0; kk < Ks; ++kk)
                bwI[G][kk] = cvt8(wih2f + (size_t)(G * 64 + col) * 128 + kk * 32 + hi * 8);
        float bb[4];
        #pragma unroll
        for (int G = 0; G < 4; ++G) bb[G] = bi2[G * 64 + col] + bh2[G * 64 + col];
        float* xq = xg2 + (size_t)blk * 1024 + col * 16;

        #pragma unroll 1
        for (int s = 0; s < 76; ++s) {
            const int cur = s & 1;
            if (s >= 1) {
                half8 air[Ks];
                #pragma unroll
                for (int kk = 0; kk < Ks; ++kk)
                    air[kk] = *(const half8*)&hp[cur][lr][kk * 32 + hi * 8];
                f32x4 acc[4];
                #pragma unroll
                for (int G = 0; G < 4; ++G)
                    acc[G] = f32x4{bb[G], bb[G], bb[G], bb[G]};
                #pragma unroll
                for (int G = 0; G < 4; ++G)
                    #pragma unroll
                    for (int kk = 0; kk < Ks; ++kk)
                        acc[G] = __builtin_amdgcn_mfma_f32_16x16x32_f16(air[kk], bwI[G][kk], acc[G], 0, 0, 0);
                if (hi == 0) {
                    #pragma unroll
                    for (int G = 0; G < 4; ++G)
                        *(f32x4*)(xq + (size_t)(s - 1) * 28672 + G * 4) = acc[G];
                }
            }
            FTAIL
        }
    }
}

// ---------------------------------------------------------------------------
// Quad-fused layers 2,3,4,5 + fused final linear (round-12 proven schedule;
// strides padded 72->96, 40->80 for 2-way bank aliasing; weights/biases
// converted from f32 at init). 25 blocks x 832 threads (13 waves).
// ---------------------------------------------------------------------------
struct QuadPtrs {
    const float* xg;       // [78][28][256][4] f32
    const float* whh2;
    const float* whh3;
    const float* wih3;
    const float* whh4;
    const float* wih4;
    const float* whh5;
    const float* wih5;
    const float* bi3; const float* bh3;
    const float* bi4; const float* bh4;
    const float* bi5; const float* bh5;
    const _Float16* lwI;   // [75][4][16][32] fp16
    const float* lb;       // [60]
    float* outF;           // [100][60]
};

__global__ __launch_bounds__(832) void lstm_quad(QuadPtrs q) {
    __shared__ __align__(16) _Float16 hb2[2][4][96], hp2[2][4][96];
    __shared__ __align__(16) _Float16 hb3[2][4][96], hp3[2][4][96];
    __shared__ __align__(16) _Float16 hb4[2][4][80], hp4[2][4][80];
    __shared__ __align__(16) _Float16 hb5[2][4][80];

    const int tid = threadIdx.x;
    const int w = tid >> 6, l = tid & 63, hi = l >> 4;
    const int lr = (l & 15) & 3;
    const int blk = blockIdx.x;

    for (int i = tid; i < 2 * 4 * 96; i += 832) {
        ((_Float16*)hb2)[i] = (_Float16)0; ((_Float16*)hp2)[i] = (_Float16)0;
        ((_Float16*)hb3)[i] = (_Float16)0; ((_Float16*)hp3)[i] = (_Float16)0;
    }
    for (int i = tid; i < 2 * 4 * 80; i += 832) {
        ((_Float16*)hb4)[i] = (_Float16)0; ((_Float16*)hp4)[i] = (_Float16)0;
        ((_Float16*)hb5)[i] = (_Float16)0;
    }
    __syncthreads();

    float cst = 0.f;

    if (w < 4) {  // ----- L2: xg C-init role -----
        const int col = w * 16 + (l & 15);
        half8 bw[4][2];
        #pragma unroll
        for (int G = 0; G < 4; ++G)
            #pragma unroll
            for (int kk = 0; kk < 2; ++kk)
                bw[G][kk] = cvt8(q.whh2 + (size_t)(G * 64 + col) * 64 + kk * 32 + hi * 8);
        const float* xp = q.xg + (size_t)blk * 1024 + col * 16;
        f32x4 P0[4], P1[4], P2[4];
#define XLOADQ(PA)                                                            \
        PA[0] = *(const f32x4*)(xp + 0);                                      \
        PA[1] = *(const f32x4*)(xp + 4);                                      \
        PA[2] = *(const f32x4*)(xp + 8);                                      \
        PA[3] = *(const f32x4*)(xp + 12);                                     \
        xp += 28672;
        XLOADQ(P0)
        XLOADQ(P1)
        XLOADQ(P2)

#define QA(PA, CUR, S)                                                        \
        {                                                                     \
            if ((S) < 75) {                                                   \
                half8 afr[2];                                                 \
                _Pragma("unroll") for (int kk = 0; kk < 2; ++kk)              \
                    afr[kk] = *(const half8*)&hb2[CUR][lr][kk * 32 + hi * 8]; \
                f32x4 aI = PA[0], aF = PA[1], aG4 = PA[2], aO = PA[3];        \
                XLOADQ(PA)                                                    \
                _Pragma("unroll") for (int kk = 0; kk < 2; ++kk) {            \
                    aI = __builtin_amdgcn_mfma_f32_16x16x32_f16(afr[kk], bw[0][kk], aI, 0, 0, 0);  \
                    aF = __builtin_amdgcn_mfma_f32_16x16x32_f16(afr[kk], bw[1][kk], aF, 0, 0, 0);  \
                    aG4 = __builtin_amdgcn_mfma_f32_16x16x32_f16(afr[kk], bw[2][kk], aG4, 0, 0, 0);\
                    aO = __builtin_amdgcn_mfma_f32_16x16x32_f16(afr[kk], bw[3][kk], aO, 0, 0, 0);  \
                }                                                             \
                ACT(aI, aF, aG4, aO)                                          \
                hb2[(CUR) ^ 1][hi][col] = hv;                                 \
                hp2[(CUR) ^ 1][hi][col] = hv;                                 \
            }                                                                 \
            FTAIL                                                             \
        }
        #pragma unroll 1
        for (int it = 0; it < 13; ++it) {
            const int b6 = it * 6;
            QA(P0, 0, b6 + 0) QA(P1, 1, b6 + 1) QA(P2, 0, b6 + 2)
            QA(P0, 1, b6 + 3) QA(P1, 0, b6 + 4) QA(P2, 1, b6 + 5)
        }
#undef QA
#undef XLOADQ
    } else if (w < 8) {  // ----- L3: H=64, HIN=64, lag 1 -----
        const int col = (w - 4) * 16 + (l & 15);
        half8 bwB[4][2], bwI[4][2];
        #pragma unroll
        for (int G = 0; G < 4; ++G)
            #pragma unroll
            for (int kk = 0; kk < 2; ++kk) {
                bwB[G][kk] = cvt8(q.whh3 + (size_t)(G * 64 + col) * 64 + kk * 32 + hi * 8);
                bwI[G][kk] = cvt8(q.wih3 + (size_t)(G * 64 + col) * 64 + kk * 32 + hi * 8);
            }
        const float bI = q.bi3[col] + q.bh3[col];
        const float bF = q.bi3[64 + col] + q.bh3[64 + col];
        const float bG = q.bi3[128 + col] + q.bh3[128 + col];
        const float bO = q.bi3[192 + col] + q.bh3[192 + col];
        #pragma unroll 1
        for (int s = 0; s < 78; ++s) {
            const int cur = s & 1;
            if (s >= 1 && s <= 75) {
                half8 afr[2], air[2];
                #pragma unroll
                for (int kk = 0; kk < 2; ++kk) {
                    afr[kk] = *(const half8*)&hb3[cur][lr][kk * 32 + hi * 8];
                    air[kk] = *(const half8*)&hp2[cur][lr][kk * 32 + hi * 8];
                }
                f32x4 aI = {bI, bI, bI, bI}, aF = {bF, bF, bF, bF};
                f32x4 aG4 = {bG, bG, bG, bG}, aO = {bO, bO, bO, bO};
                #pragma unroll
                for (int kk = 0; kk < 2; ++kk) {
                    aI = __builtin_amdgcn_mfma_f32_16x16x32_f16(afr[kk], bwB[0][kk], aI, 0, 0, 0);
                    aF = __builtin_amdgcn_mfma_f32_16x16x32_f16(afr[kk], bwB[1][kk], aF, 0, 0, 0);
                    aG4 = __builtin_amdgcn_mfma_f32_16x16x32_f16(afr[kk], bwB[2][kk], aG4, 0, 0, 0);
                    aO = __builtin_amdgcn_mfma_f32_16x16x32_f16(afr[kk], bwB[3][kk], aO, 0, 0, 0);
                }
                #pragma unroll
                for (int kk = 0; kk < 2; ++kk) {
                    aI = __builtin_amdgcn_mfma_f32_16x16x32_f16(air[kk], bwI[0][kk], aI, 0, 0, 0);
                    aF = __builtin_amdgcn_mfma_f32_16x16x32_f16(air[kk], bwI[1][kk], aF, 0, 0, 0);
                    aG4 = __builtin_amdgcn_mfma_f32_16x16x32_f16(air[kk], bwI[2][kk], aG4, 0, 0, 0);
                    aO = __builtin_amdgcn_mfma_f32_16x16x32_f16(air[kk], bwI[3][kk], aO, 0, 0, 0);
                }
                ACT(aI, aF, aG4, aO)
                hb3[cur ^ 1][hi][col] = hv;
                hp3[cur ^ 1][hi][col] = hv;
            }
            FTAIL
        }
    } else if (w < 10) {  // ----- L4: H=32, HIN=64, lag 2 -----
        const int col = (w - 8) * 16 + (l & 15);
        half8 bwB[4], bwI[4][2];
        #pragma unroll
        for (int G = 0; G < 4; ++G) {
            bwB[G] = cvt8(q.whh4 + (size_t)(G * 32 + col) * 32 + hi * 8);
            #pragma unroll
            for (int kk = 0; kk < 2; ++kk)
                bwI[G][kk] = cvt8(q.wih4 + (size_t)(G * 32 + col) * 64 + kk * 32 + hi * 8);
        }
        const float bI = q.bi4[col] + q.bh4[col];
        const float bF = q.bi4[32 + col] + q.bh4[32 + col];
        const float bG = q.bi4[64 + col] + q.bh4[64 + col];
        const float bO = q.bi4[96 + col] + q.bh4[96 + col];
        #pragma unroll 1
        for (int s = 0; s < 78; ++s) {
            const int cur = s & 1;
            if (s >= 2 && s <= 76) {
                half8 afr = *(const half8*)&hb4[cur][lr][hi * 8];
                half8 air[2];
                #pragma unroll
                for (int kk = 0; kk < 2; ++kk)
                    air[kk] = *(const half8*)&hp3[cur][lr][kk * 32 + hi * 8];
                f32x4 aI = {bI, bI, bI, bI}, aF = {bF, bF, bF, bF};
                f32x4 aG4 = {bG, bG, bG, bG}, aO = {bO, bO, bO, bO};
                aI = __builtin_amdgcn_mfma_f32_16x16x32_f16(afr, bwB[0], aI, 0, 0, 0);
                aF = __builtin_amdgcn_mfma_f32_16x16x32_f16(afr, bwB[1], aF, 0, 0, 0);
                aG4 = __builtin_amdgcn_mfma_f32_16x16x32_f16(afr, bwB[2], aG4, 0, 0, 0);
                aO = __builtin_amdgcn_mfma_f32_16x16x32_f16(afr, bwB[3], aO, 0, 0, 0);
                #pragma unroll
                for (int kk = 0; kk < 2; ++kk) {
                    aI = __builtin_amdgcn_mfma_f32_16x16x32_f16(air[kk], bwI[0][kk], aI, 0, 0, 0);
                    aF = __builtin_amdgcn_mfma_f32_16x16x32_f16(air[kk], bwI[1][kk], aF, 0, 0, 0);
                    aG4 = __builtin_amdgcn_mfma_f32_16x16x32_f16(air[kk], bwI[2][kk], aG4, 0, 0, 0);
                    aO = __builtin_amdgcn_mfma_f32_16x16x32_f16(air[kk], bwI[3][kk], aO, 0, 0, 0);
                }
                ACT(aI, aF, aG4, aO)
                hb4[cur ^ 1][hi][col] = hv;
                hp4[cur ^ 1][hi][col] = hv;
            }
            FTAIL
        }
    } else if (w < 12) {  // ----- L5: H=32, HIN=32, lag 3; publishes hb5 -----
        const int col = (w - 10) * 16 + (l & 15);
        half8 bwB[4], bwI[4];
        #pragma unroll
        for (int G = 0; G < 4; ++G) {
            bwB[G] = cvt8(q.whh5 + (size_t)(G * 32 + col) * 32 + hi * 8);
            bwI[G] = cvt8(q.wih5 + (size_t)(G * 32 + col) * 32 + hi * 8);
        }
        const float bI = q.bi5[col] + q.bh5[col];
        const float bF = q.bi5[32 + col] + q.bh5[32 + col];
        const float bG = q.bi5[64 + col] + q.bh5[64 + col];
        const float bO = q.bi5[96 + col] + q.bh5[96 + col];
        #pragma unroll 1
        for (int s = 0; s < 78; ++s) {
            const int cur = s & 1;
            if (s >= 3) {
                half8 afr = *(const half8*)&hb5[cur][lr][hi * 8];
                half8 air = *(const half8*)&hp4[cur][lr][hi * 8];
                f32x4 aI = {bI, bI, bI, bI}, aF = {bF, bF, bF, bF};
                f32x4 aG4 = {bG, bG, bG, bG}, aO = {bO, bO, bO, bO};
                aI = __builtin_amdgcn_mfma_f32_16x16x32_f16(afr, bwB[0], aI, 0, 0, 0);
                aF = __builtin_amdgcn_mfma_f32_16x16x32_f16(afr, bwB[1], aF, 0, 0, 0);
                aG4 = __builtin_amdgcn_mfma_f32_16x16x32_f16(afr, bwB[2], aG4, 0, 0, 0);
                aO = __builtin_amdgcn_mfma_f32_16x16x32_f16(afr, bwB[3], aO, 0, 0, 0);
                aI = __builtin_amdgcn_mfma_f32_16x16x32_f16(air, bwI[0], aI, 0, 0, 0);
                aF = __builtin_amdgcn_mfma_f32_16x16x32_f16(air, bwI[1], aF, 0, 0, 0);
                aG4 = __builtin_amdgcn_mfma_f32_16x16x32_f16(air, bwI[2], aG4, 0, 0, 0);
                aO = __builtin_amdgcn_mfma_f32_16x16x32_f16(air, bwI[3], aO, 0, 0, 0);
                ACT(aI, aF, aG4, aO)
                hb5[cur ^ 1][hi][col] = hv;
            }
            FTAIL
        }
    } else {  // ----- LIN: lag 4 -----
        const int ln = l & 15;
        const _Float16* lwp = q.lwI + (size_t)ln * 32 + hi * 8;
        half8 LA[4], LB[4];
        #pragma unroll
        for (int tl = 0; tl < 4; ++tl) {
            LA[tl] = *(const half8*)(lwp + (size_t)(0 * 4 + tl) * 512);
            LB[tl] = *(const half8*)(lwp + (size_t)(1 * 4 + tl) * 512);
        }
        f32x4 acc[4];
        #pragma unroll
        for (int tl = 0; tl < 4; ++tl) acc[tl] = f32x4{0.f, 0.f, 0.f, 0.f};

        #pragma unroll 1
        for (int it = 0; it < 39; ++it) {
            {  // even step s0 = 2*it, t = s0 - 4, reads hb5[0], uses LA
                int t = 2 * it - 4;
                if (t >= 0) {
                    half8 hf = *(const half8*)&hb5[0][lr][hi * 8];
                    #pragma unroll
                    for (int tl = 0; tl < 4; ++tl)
                        acc[tl] = __builtin_amdgcn_mfma_f32_16x16x32_f16(LA[tl], hf, acc[tl], 0, 0, 0);
                }
                int tn = t + 2;
                if (tn < 0) tn = 0;
                if (tn > 74) tn = 74;
                #pragma unroll
                for (int tl = 0; tl < 4; ++tl)
                    LA[tl] = *(const half8*)(lwp + ((size_t)tn * 4 + tl) * 512);
                FTAIL
            }
            {  // odd step s1 = 2*it+1, t = s1 - 4, reads hb5[1], uses LB
                int t = 2 * it - 3;
                if (t >= 0) {
                    half8 hf = *(const half8*)&hb5[1][lr][hi * 8];
                    #pragma unroll
                    for (int tl = 0; tl < 4; ++tl)
                        acc[tl] = __builtin_amdgcn_mfma_f32_16x16x32_f16(LB[tl], hf, acc[tl], 0, 0, 0);
                }
                int tn = t + 2;
                if (tn < 0) tn = 0;
                if (tn > 74) tn = 74;
                #pragma unroll
                for (int tl = 0; tl < 4; ++tl)
                    LB[tl] = *(const half8*)(lwp + ((size_t)tn * 4 + tl) * 512);
                FTAIL
            }
        }
        {  // post-loop: t = 74 (hb5[0] stable after final barrier)
            half8 hf = *(const half8*)&hb5[0][lr][hi * 8];
            #pragma unroll
            for (int tl = 0; tl < 4; ++tl)
                acc[tl] = __builtin_amdgcn_mfma_f32_16x16x32_f16(LA[tl], hf, acc[tl], 0, 0, 0);
        }
        if (ln < 4) {
            int b = blk * 4 + ln;
            #pragma unroll
            for (int tl = 0; tl < 4; ++tl)
                #pragma unroll
                for (int r = 0; r < 4; ++r) {
                    int o = tl * 16 + hi * 4 + r;
                    if (o < 60) q.outF[b * 60 + o] = acc[tl][r] + q.lb[o];
                }
        }
    }
}

// ---------------------------------------------------------------------------
extern "C" void kernel_launch(void* const* d_in, const int* in_sizes, int n_in,
                              void* d_out, int out_size, void* d_ws, size_t ws_size,
                              hipStream_t stream) {
    const float* x = (const float*)d_in[0];
    const float* wih[6];
    const float* whhp[6];
    const float* bih[6];
    const float* bhh[6];
    for (int i = 0; i < 6; ++i) {
        wih[i] = (const float*)d_in[1 + 4 * i];
        whhp[i] = (const float*)d_in[2 + 4 * i];
        bih[i] = (const float*)d_in[3 + 4 * i];
        bhh[i] = (const float*)d_in[4 + 4 * i];
    }
    const float* lw = (const float*)d_in[25];
    const float* lb = (const float*)d_in[26];
    float* out = (float*)d_out;

    char* ws = (char*)d_ws;
    size_t cur = 0;
    auto alloc = [&](size_t b) {
        size_t o = cur;
        cur += (b + 255) & ~(size_t)255;
        return o;
    };
    _Float16* lwI = (_Float16*)(ws + alloc(153600 * 2));
    float* xgA = (float*)(ws + alloc((size_t)78 * 28 * 512 * 4 * 4));   // xg0, then xg1
    float* xgB = (float*)(ws + alloc((size_t)78 * 28 * 256 * 4 * 4));   // xg2
    _Float16* h0 = (_Float16*)(ws + alloc((size_t)75 * 112 * 128 * 2));

    prep_lw<<<600, 256, 0, stream>>>(lw, lwI);

    // layer 0: xg from f32 x + f32 wih0, then recurrence (writes h0)
    gemm_xg0<<<dim3(150, 8), 256, 0, stream>>>(x, wih[0], bih[0], bhh[0], xgA);
    lstm_rec0<<<25, 512, 0, stream>>>(xgA, whhp[0], h0);
    // layer 1: xg from h0 + f32 wih1 (reuses xgA), then rec1 + on-the-fly xg2
    gemm_xg1<<<dim3(150, 8), 256, 0, stream>>>(h0, wih[1], bih[1], bhh[1], xgA);
    rec1xg<<<25, 768, 0, stream>>>(xgA, whhp[1], wih[2], bih[2], bhh[2], xgB);
    // layers 2..5 + final linear, all fused
    QuadPtrs q;
    q.xg = xgB;
    q.whh2 = whhp[2]; q.whh3 = whhp[3]; q.wih3 = wih[3];
    q.whh4 = whhp[4]; q.wih4 = wih[4]; q.whh5 = whhp[5]; q.wih5 = wih[5];
    q.bi3 = bih[3]; q.bh3 = bhh[3];
    q.bi4 = bih[4]; q.bh4 = bhh[4];
    q.bi5 = bih[5]; q.bh5 = bhh[5];
    q.lwI = lwI; q.lb = lb; q.outF = out;
    lstm_quad<<<25, 832, 0, stream>>>(q);
}